// Round 2
// baseline (335.646 us; speedup 1.0000x reference)
//
#include <hip/hip_runtime.h>
#include <hip/hip_bf16.h>
#include <stdint.h>

#define ENC_DIM 2048
#define ATT_DIM 512
#define BATCH   256
#define NPIX    196
#define MTOT    (BATCH*NPIX)          // 50176
#define CTX_OFF (BATCH*ENC_DIM)       // context, then alpha
#define KC      32                    // K-chunk
#define NCHUNK  (ENC_DIM/KC)          // 64

typedef __attribute__((ext_vector_type(8))) short  short8;
typedef __attribute__((ext_vector_type(4))) float  f32x4;

__device__ __forceinline__ unsigned int f2bf(float x) {
    union { float f; uint32_t u; } v; v.f = x;
    return (v.u + 0x7FFFu + ((v.u >> 16) & 1u)) >> 16;
}

__device__ __forceinline__ void gll16(const void* g, void* l) {
    __builtin_amdgcn_global_load_lds(
        (const __attribute__((address_space(1))) unsigned int*)g,
        (__attribute__((address_space(3))) unsigned int*)l, 16, 0, 0);
}

// ---------------------------------------------------------------------------
// Kernel 0: pack W_enc (fp32 [2048][512]) -> bf16 Wp[(k/8)*512 + n][8]
// ---------------------------------------------------------------------------
__global__ __launch_bounds__(256) void pack_wenc(const float* __restrict__ W,
                                                 unsigned short* __restrict__ Wp) {
    const int i  = blockIdx.x * 256 + threadIdx.x;   // 0 .. 131071
    const int n  = i & 511;
    const int kg = i >> 9;
    short8 v;
#pragma unroll
    for (int j = 0; j < 8; ++j)
        v[j] = (short)f2bf(W[(size_t)(kg * 8 + j) * 512 + n]);
    *(short8*)(Wp + (size_t)i * 8) = v;
}

// ---------------------------------------------------------------------------
// Kernel 1: att2p[b][a] = hidden[b,:] @ W_dec[:,a] + b_dec[a] + b_enc[a]
// ---------------------------------------------------------------------------
__global__ __launch_bounds__(256) void att2_kernel(const float* __restrict__ hidden,
                                                   const float* __restrict__ Wdec,
                                                   const float* __restrict__ bdec,
                                                   const float* __restrict__ benc,
                                                   float* __restrict__ att2p) {
    __shared__ float h[512];
    const int b   = blockIdx.x;
    const int tid = threadIdx.x;
    h[tid]       = hidden[(size_t)b * 512 + tid];
    h[tid + 256] = hidden[(size_t)b * 512 + tid + 256];
    __syncthreads();
    float acc0 = bdec[tid]       + benc[tid];
    float acc1 = bdec[tid + 256] + benc[tid + 256];
#pragma unroll 4
    for (int k = 0; k < 512; ++k) {
        const float hk = h[k];
        acc0 = fmaf(hk, Wdec[(size_t)k * 512 + tid],       acc0);
        acc1 = fmaf(hk, Wdec[(size_t)k * 512 + tid + 256], acc1);
    }
    att2p[(size_t)b * 512 + tid]       = acc0;
    att2p[(size_t)b * 512 + tid + 256] = acc1;
}

// ---------------------------------------------------------------------------
// Kernel 2: scores via 64x512 MFMA tile, double-buffered KC=32 chunks.
// B: global_load_lds (linear). A: reg-staged fp32->bf16, XOR-swizzled slots.
// ---------------------------------------------------------------------------
__global__ __launch_bounds__(512, 4) void score_kernel(const float* __restrict__ enc,
                                                       const unsigned short* __restrict__ Wp,
                                                       const float* __restrict__ att2p,
                                                       const float* __restrict__ Wfull,
                                                       float* __restrict__ scores) {
    __shared__ __align__(16) unsigned short ldsA[2][64 * KC];      // 2 x 4 KB
    __shared__ __align__(16) unsigned short ldsB[2][4 * 512 * 8];  // 2 x 32 KB
    __shared__ float lds_att2[2][ATT_DIM];
    __shared__ float lds_wf[ATT_DIM];
    __shared__ float lds_sc[64];

    const int tid = threadIdx.x;
    const int w   = tid >> 6;
    const int l   = tid & 63;
    const int m0  = blockIdx.x * 64;
    const int b0  = m0 / NPIX;
    const int b1  = (m0 + 63) / NPIX;

    lds_att2[0][tid] = att2p[(size_t)b0 * ATT_DIM + tid];
    lds_att2[1][tid] = att2p[(size_t)b1 * ATT_DIM + tid];
    lds_wf[tid] = Wfull[tid];
    if (tid < 64) lds_sc[tid] = 0.0f;

    f32x4 acc[4][4];
#pragma unroll
    for (int i = 0; i < 4; ++i)
#pragma unroll
        for (int j = 0; j < 4; ++j)
            acc[i][j] = (f32x4){0.f, 0.f, 0.f, 0.f};

    // ---- A staging geometry: thread -> (row, 4-float group) ----
    const int ar  = tid >> 3;                 // 0..63
    const int ah  = tid & 7;                  // 0..7 (4 floats each)
    const int axr = (ar >> 1) & 3;            // slot XOR key
    const float* aG = enc + (size_t)(m0 + ar) * ENC_DIM + ah * 4;
    const int a_wr_off = ar * KC + ((ah >> 1) ^ axr) * 8 + (ah & 1) * 4;  // shorts

    // ---- B staging geometry: 32 segments of 1 KB, wave w owns 4 ----
    const unsigned char* WpB = (const unsigned char*)Wp;

    // ---- fragment read offsets (in shorts), chunk-invariant ----
    int a_rd[4], b_rd[4];
#pragma unroll
    for (int mf = 0; mf < 4; ++mf) {
        const int r = mf * 16 + (l & 15);
        a_rd[mf] = r * KC + (((l >> 4) ^ ((r >> 1) & 3)) * 8);
    }
#pragma unroll
    for (int nf = 0; nf < 4; ++nf) {
        const int col = w * 64 + nf * 16 + (l & 15);
        b_rd[nf] = ((l >> 4) * 512 + col) * 8;
    }

    // ---- prologue: stage chunk 0 into buffer 0 ----
#pragma unroll
    for (int it = 0; it < 4; ++it) {
        const int seg = w * 4 + it;
        gll16(WpB + (size_t)seg * 1024 + l * 16,
              (unsigned char*)ldsB[0] + seg * 1024 + l * 16);
    }
    {
        f32x4 a0 = *(const f32x4*)aG;
        uint32_t* dst = (uint32_t*)(ldsA[0] + a_wr_off);
        dst[0] = f2bf(a0[0]) | (f2bf(a0[1]) << 16);
        dst[1] = f2bf(a0[2]) | (f2bf(a0[3]) << 16);
    }
    __syncthreads();

#pragma unroll 2
    for (int c = 0; c < NCHUNK - 1; ++c) {
        const int p = c & 1;
        // ---- issue next-chunk staging early (T14) ----
#pragma unroll
        for (int it = 0; it < 4; ++it) {
            const int seg = w * 4 + it;
            gll16(WpB + (size_t)(c + 1) * 32768 + seg * 1024 + l * 16,
                  (unsigned char*)ldsB[p ^ 1] + seg * 1024 + l * 16);
        }
        f32x4 an = *(const f32x4*)(aG + (c + 1) * KC);
        // ---- compute current chunk ----
        short8 af[4], bfv[4];
#pragma unroll
        for (int mf = 0; mf < 4; ++mf) af[mf]  = *(const short8*)(ldsA[p] + a_rd[mf]);
#pragma unroll
        for (int nf = 0; nf < 4; ++nf) bfv[nf] = *(const short8*)(ldsB[p] + b_rd[nf]);
#pragma unroll
        for (int mf = 0; mf < 4; ++mf)
#pragma unroll
            for (int nf = 0; nf < 4; ++nf)
                acc[mf][nf] = __builtin_amdgcn_mfma_f32_16x16x32_bf16(
                    af[mf], bfv[nf], acc[mf][nf], 0, 0, 0);
        // ---- write A for next chunk (late) ----
        {
            uint32_t* dst = (uint32_t*)(ldsA[p ^ 1] + a_wr_off);
            dst[0] = f2bf(an[0]) | (f2bf(an[1]) << 16);
            dst[1] = f2bf(an[2]) | (f2bf(an[3]) << 16);
        }
        __syncthreads();
    }
    // ---- final chunk (buffer 1) ----
    {
        const int p = (NCHUNK - 1) & 1;
        short8 af[4], bfv[4];
#pragma unroll
        for (int mf = 0; mf < 4; ++mf) af[mf]  = *(const short8*)(ldsA[p] + a_rd[mf]);
#pragma unroll
        for (int nf = 0; nf < 4; ++nf) bfv[nf] = *(const short8*)(ldsB[p] + b_rd[nf]);
#pragma unroll
        for (int mf = 0; mf < 4; ++mf)
#pragma unroll
            for (int nf = 0; nf < 4; ++nf)
                acc[mf][nf] = __builtin_amdgcn_mfma_f32_16x16x32_bf16(
                    af[mf], bfv[nf], acc[mf][nf], 0, 0, 0);
    }

    // ---- epilogue: bias + relu + dot(Wf), reduce to per-row scores ----
#pragma unroll
    for (int mf = 0; mf < 4; ++mf) {
#pragma unroll
        for (int reg = 0; reg < 4; ++reg) {
            const int row = mf * 16 + ((l >> 4) << 2) + reg;
            const int sel = ((m0 + row) >= (b0 + 1) * NPIX) ? 1 : 0;
            float sv = 0.0f;
#pragma unroll
            for (int nf = 0; nf < 4; ++nf) {
                const int col = (w << 6) + (nf << 4) + (l & 15);
                float v = acc[mf][nf][reg] + lds_att2[sel][col];
                v = fmaxf(v, 0.0f);
                sv = fmaf(v, lds_wf[col], sv);
            }
            sv += __shfl_xor(sv, 8);
            sv += __shfl_xor(sv, 4);
            sv += __shfl_xor(sv, 2);
            sv += __shfl_xor(sv, 1);
            if ((l & 15) == 0) atomicAdd(&lds_sc[row], sv);
        }
    }
    __syncthreads();
    if (tid < 64) scores[m0 + tid] = lds_sc[tid];
}

// ---------------------------------------------------------------------------
// Kernel 3: softmax + context. grid = B x 4 e-quarters; 256 thr;
// thread owns float4 of e, covers half the pixels; LDS combine.
// ---------------------------------------------------------------------------
__global__ __launch_bounds__(256) void ctx_kernel(const float* __restrict__ enc,
                                                  const float* __restrict__ scores,
                                                  float* __restrict__ out) {
    __shared__ float salpha[NPIX];
    __shared__ float red[8];
    __shared__ float partial[512];
    const int tid  = threadIdx.x;
    const int lane = tid & 63;
    const int wid  = tid >> 6;
    const int b    = blockIdx.x >> 2;
    const int eq   = blockIdx.x & 3;

    const float sv = (tid < NPIX) ? scores[(size_t)b * NPIX + tid] : -1e30f;
    float mx = sv;
#pragma unroll
    for (int m = 32; m >= 1; m >>= 1) mx = fmaxf(mx, __shfl_xor(mx, m));
    if (lane == 0) red[wid] = mx;
    __syncthreads();
    if (tid == 0) red[4] = fmaxf(fmaxf(red[0], red[1]), fmaxf(red[2], red[3]));
    __syncthreads();
    const float bm = red[4];
    const float ex = (tid < NPIX) ? __expf(sv - bm) : 0.0f;
    float sm = ex;
#pragma unroll
    for (int m = 32; m >= 1; m >>= 1) sm += __shfl_xor(sm, m);
    if (lane == 0) red[wid] = sm;
    __syncthreads();
    if (tid == 0) red[5] = red[0] + red[1] + red[2] + red[3];
    __syncthreads();
    const float inv = 1.0f / red[5];
    if (tid < NPIX) {
        const float av = ex * inv;
        salpha[tid] = av;
        if (eq == 0) out[CTX_OFF + (size_t)b * NPIX + tid] = av;
    }
    __syncthreads();

    const int l128 = tid & 127;
    const int ph   = tid >> 7;
    const float* ep = enc + (size_t)b * NPIX * ENC_DIM + eq * 512 + l128 * 4;
    f32x4 acc = (f32x4){0.f, 0.f, 0.f, 0.f};
#pragma unroll 4
    for (int n = ph; n < NPIX; n += 2) {
        const float al = salpha[n];
        f32x4 v = *(const f32x4*)(ep + (size_t)n * ENC_DIM);
        acc += v * al;
    }
    if (ph == 1) *(f32x4*)(partial + l128 * 4) = acc;
    __syncthreads();
    if (ph == 0) {
        f32x4 o = acc + *(const f32x4*)(partial + l128 * 4);
        *(f32x4*)(out + (size_t)b * ENC_DIM + eq * 512 + l128 * 4) = o;
    }
}

// ---------------------------------------------------------------------------
extern "C" void kernel_launch(void* const* d_in, const int* in_sizes, int n_in,
                              void* d_out, int out_size, void* d_ws, size_t ws_size,
                              hipStream_t stream) {
    const float* enc    = (const float*)d_in[0];
    const float* hidden = (const float*)d_in[1];
    const float* Wenc   = (const float*)d_in[2];
    const float* benc   = (const float*)d_in[3];
    const float* Wdec   = (const float*)d_in[4];
    const float* bdec   = (const float*)d_in[5];
    const float* Wfull  = (const float*)d_in[6];
    // d_in[7] = b_full: softmax-shift-invariant, unused.
    float* out = (float*)d_out;

    unsigned short* Wp    = (unsigned short*)d_ws;                              // 2 MB
    float*          att2p = (float*)((char*)d_ws + (2u << 20));                 // 512 KB
    float*          scores= (float*)((char*)d_ws + (2u << 20) + (512u << 10));  // 200 KB

    pack_wenc  <<<512, 256, 0, stream>>>(Wenc, Wp);
    att2_kernel<<<BATCH, 256, 0, stream>>>(hidden, Wdec, bdec, benc, att2p);
    score_kernel<<<MTOT / 64, 512, 0, stream>>>(enc, Wp, att2p, Wfull, scores);
    ctx_kernel <<<BATCH * 4, 256, 0, stream>>>(enc, scores, out);
}

// Round 3
// 289.073 us; speedup vs baseline: 1.1611x; 1.1611x over previous
//
#include <hip/hip_runtime.h>
#include <hip/hip_bf16.h>
#include <stdint.h>

#define ENC_DIM 2048
#define ATT_DIM 512
#define BATCH   256
#define NPIX    196
#define MROWS   (BATCH*NPIX)          // 50176
#define CTX_OFF (BATCH*ENC_DIM)       // context, then alpha
#define KC      128                   // K per chunk
#define NCH     (ENC_DIM/KC)          // 16
#define MSUB    112                   // rows per M-subtile (7 x 16)
#define ABUF    (MSUB*KC*2)           // 28672 bytes per A buffer

typedef __attribute__((ext_vector_type(8))) short  short8;
typedef __attribute__((ext_vector_type(4))) float  f32x4;

__device__ __forceinline__ uint32_t f2bf(float x) {
    union { float f; uint32_t u; } v; v.f = x;
    return (v.u + 0x7FFFu + ((v.u >> 16) & 1u)) >> 16;
}

// ---------------------------------------------------------------------------
// Kernel 0: pack W_enc (fp32 [2048][512]) -> bf16 Wp[(k/8)*512 + n][8]
// ---------------------------------------------------------------------------
__global__ __launch_bounds__(256) void pack_wenc(const float* __restrict__ W,
                                                 unsigned short* __restrict__ Wp) {
    const int i  = blockIdx.x * 256 + threadIdx.x;   // 0 .. 131071
    const int n  = i & 511;
    const int kg = i >> 9;
    short8 v;
#pragma unroll
    for (int j = 0; j < 8; ++j)
        v[j] = (short)f2bf(W[(size_t)(kg * 8 + j) * 512 + n]);
    *(short8*)(Wp + (size_t)i * 8) = v;
}

// ---------------------------------------------------------------------------
// Kernel 1: att2p[b][a] = hidden[b,:] @ W_dec[:,a] + b_dec[a] + b_enc[a]
// ---------------------------------------------------------------------------
__global__ __launch_bounds__(256) void att2_kernel(const float* __restrict__ hidden,
                                                   const float* __restrict__ Wdec,
                                                   const float* __restrict__ bdec,
                                                   const float* __restrict__ benc,
                                                   float* __restrict__ att2p) {
    __shared__ float h[512];
    const int b   = blockIdx.x;
    const int tid = threadIdx.x;
    h[tid]       = hidden[(size_t)b * 512 + tid];
    h[tid + 256] = hidden[(size_t)b * 512 + tid + 256];
    __syncthreads();
    float acc0 = bdec[tid]       + benc[tid];
    float acc1 = bdec[tid + 256] + benc[tid + 256];
#pragma unroll 4
    for (int k = 0; k < 512; ++k) {
        const float hk = h[k];
        acc0 = fmaf(hk, Wdec[(size_t)k * 512 + tid],       acc0);
        acc1 = fmaf(hk, Wdec[(size_t)k * 512 + tid + 256], acc1);
    }
    att2p[(size_t)b * 512 + tid]       = acc0;
    att2p[(size_t)b * 512 + tid + 256] = acc1;
}

// ---------------------------------------------------------------------------
// Fused kernel: one block per batch. 512 threads = 8 waves (1M x 8N).
// Phase 1: scores[196] via MFMA (2 subtiles of 112 rows, KC=128 chunks,
//          A dbuf LDS + XOR swizzle, B direct from L2).
// Phase 2: block softmax. Phase 3: context = alpha @ enc[b].
// ---------------------------------------------------------------------------
__global__ __launch_bounds__(512, 2) void fused_kernel(const float* __restrict__ enc,
                                                       const unsigned short* __restrict__ Wp,
                                                       const float* __restrict__ att2p,
                                                       const float* __restrict__ Wfull,
                                                       float* __restrict__ out) {
    __shared__ __align__(16) unsigned char ldsA[2 * ABUF];   // 56 KB
    __shared__ float lds_att2[ATT_DIM];
    __shared__ float lds_wf[ATT_DIM];
    __shared__ float lds_sc[224];
    __shared__ float salpha[NPIX];
    __shared__ float red[16];

    const int tid = threadIdx.x;
    const int w   = tid >> 6;        // wave 0..7 (owns cols [64w, 64w+64))
    const int l   = tid & 63;
    const int b   = blockIdx.x;

    lds_att2[tid] = att2p[(size_t)b * ATT_DIM + tid];
    lds_wf[tid]   = Wfull[tid];
    if (tid < 224) lds_sc[tid] = 0.0f;

    // ---- B global offsets (shorts from Wp), 4 col-frags per wave ----
    int boff[4];
#pragma unroll
    for (int nf = 0; nf < 4; ++nf)
        boff[nf] = (((l >> 4) * 512) + (w << 6) + (nf << 4) + (l & 15)) * 8;

    // ---- A staging geometry ----
    const int g  = tid & 31;         // k-group (4 floats)
    const int rr = tid >> 5;         // base row 0..15
    // swizzled LDS write offset, row-linear part (i * 4096 added per i)
    const int aoffL0 = rr * 256 + (((g >> 1) ^ (rr & 7)) << 4) + ((g & 1) << 3);
    // A frag read: per-step swizzle key is l&7 (row&7 == l&7 for frag rows)
    const int axk   = l & 7;
    const int afrow = (l & 15) << 8;   // row-part of frag byte offset (+ mf*4096)

    for (int sub = 0; sub < 2; ++sub) {
        // per-subtile A row offsets (floats), clamped for the final pad rows
        int rowOff[7];
#pragma unroll
        for (int i = 0; i < 7; ++i) {
            int grow = b * NPIX + sub * MSUB + rr + 16 * i;
            if (grow > MROWS - 1) grow = MROWS - 1;
            rowOff[i] = grow * ENC_DIM;   // < 2^31
        }
        const float* aBase = enc + g * 4;

        f32x4 acc[7][4];
#pragma unroll
        for (int i = 0; i < 7; ++i)
#pragma unroll
            for (int j = 0; j < 4; ++j)
                acc[i][j] = (f32x4){0.f, 0.f, 0.f, 0.f};

        // ---- prologue: stage chunk 0 into buffer 0 ----
        {
            f32x4 sA[7];
#pragma unroll
            for (int i = 0; i < 7; ++i) sA[i] = *(const f32x4*)(aBase + rowOff[i]);
#pragma unroll
            for (int i = 0; i < 7; ++i) {
                uint2 u;
                u.x = f2bf(sA[i][0]) | (f2bf(sA[i][1]) << 16);
                u.y = f2bf(sA[i][2]) | (f2bf(sA[i][3]) << 16);
                *(uint2*)(ldsA + aoffL0 + i * 4096) = u;
            }
        }
        __syncthreads();

        for (int c = 0; c < NCH; ++c) {
            const int p = c & 1;
            const unsigned char* ldsR = ldsA + p * ABUF;
            unsigned char*       ldsW = ldsA + (p ^ 1) * ABUF;
            const bool more = (c < NCH - 1);

            // issue next-chunk A loads early (latency hides under MFMAs)
            f32x4 sA[7];
            if (more) {
#pragma unroll
                for (int i = 0; i < 7; ++i)
                    sA[i] = *(const f32x4*)(aBase + rowOff[i] + (c + 1) * KC);
            }

            const unsigned short* bC = Wp + (size_t)c * 65536;
            short8 bf0[8], bf1[8];
#pragma unroll
            for (int s2 = 0; s2 < 2; ++s2)
#pragma unroll
                for (int nf = 0; nf < 4; ++nf)
                    bf0[s2 * 4 + nf] = *(const short8*)(bC + boff[nf] + s2 * 16384);

#define STEP(S, BARR, BASE)                                                        \
            {                                                                      \
                const int so = ((((S) * 4) + (l >> 4)) ^ axk) << 4;                \
                _Pragma("unroll")                                                  \
                for (int mf = 0; mf < 7; ++mf) {                                   \
                    short8 af = *(const short8*)(ldsR + afrow + so + mf * 4096);   \
                    _Pragma("unroll")                                              \
                    for (int nf = 0; nf < 4; ++nf)                                 \
                        acc[mf][nf] = __builtin_amdgcn_mfma_f32_16x16x32_bf16(     \
                            af, BARR[(BASE) + nf], acc[mf][nf], 0, 0, 0);          \
                }                                                                  \
            }

            STEP(0, bf0, 0)
#pragma unroll
            for (int s2 = 0; s2 < 2; ++s2)
#pragma unroll
                for (int nf = 0; nf < 4; ++nf)
                    bf1[s2 * 4 + nf] = *(const short8*)(bC + boff[nf] + (2 + s2) * 16384);
            STEP(1, bf0, 4)
            STEP(2, bf1, 0)
            STEP(3, bf1, 4)
#undef STEP

            if (more) {
#pragma unroll
                for (int i = 0; i < 7; ++i) {
                    uint2 u;
                    u.x = f2bf(sA[i][0]) | (f2bf(sA[i][1]) << 16);
                    u.y = f2bf(sA[i][2]) | (f2bf(sA[i][3]) << 16);
                    *(uint2*)(ldsW + aoffL0 + i * 4096) = u;
                }
            }
            __syncthreads();
        }

        // ---- epilogue: bias + relu + dot(Wf) -> per-row partial scores ----
#pragma unroll
        for (int mf = 0; mf < 7; ++mf) {
#pragma unroll
            for (int reg = 0; reg < 4; ++reg) {
                const int row = sub * MSUB + mf * 16 + ((l >> 4) << 2) + reg;
                float sv = 0.0f;
#pragma unroll
                for (int nf = 0; nf < 4; ++nf) {
                    const int col = (w << 6) + (nf << 4) + (l & 15);
                    float v = acc[mf][nf][reg] + lds_att2[col];
                    v = fmaxf(v, 0.0f);
                    sv = fmaf(v, lds_wf[col], sv);
                }
                sv += __shfl_xor(sv, 8);
                sv += __shfl_xor(sv, 4);
                sv += __shfl_xor(sv, 2);
                sv += __shfl_xor(sv, 1);
                if ((l & 15) == 0 && row < NPIX) atomicAdd(&lds_sc[row], sv);
            }
        }
    }
    __syncthreads();

    // ---- softmax over 196 pixels (all 8 waves) ----
    const float sval = (tid < NPIX) ? lds_sc[tid] : -1e30f;
    float mx = sval;
#pragma unroll
    for (int m = 32; m >= 1; m >>= 1) mx = fmaxf(mx, __shfl_xor(mx, m));
    if (l == 0) red[w] = mx;
    __syncthreads();
    if (tid == 0) {
        float m2 = red[0];
#pragma unroll
        for (int i = 1; i < 8; ++i) m2 = fmaxf(m2, red[i]);
        red[8] = m2;
    }
    __syncthreads();
    const float bm = red[8];
    const float ex = (tid < NPIX) ? __expf(sval - bm) : 0.0f;
    float sm = ex;
#pragma unroll
    for (int m = 32; m >= 1; m >>= 1) sm += __shfl_xor(sm, m);
    if (l == 0) red[w] = sm;
    __syncthreads();
    if (tid == 0) {
        float s2 = 0.f;
#pragma unroll
        for (int i = 0; i < 8; ++i) s2 += red[i];
        red[9] = s2;
    }
    __syncthreads();
    const float inv = 1.0f / red[9];
    if (tid < NPIX) {
        const float av = ex * inv;
        salpha[tid] = av;
        out[CTX_OFF + (size_t)b * NPIX + tid] = av;
    }
    __syncthreads();

    // ---- phase 3: context[b, :] = sum_n alpha[n] * enc[b, n, :] ----
    const float* ep = enc + (size_t)b * NPIX * ENC_DIM + tid * 4;
    f32x4 a2 = (f32x4){0.f, 0.f, 0.f, 0.f};
#pragma unroll 4
    for (int n = 0; n < NPIX; ++n)
        a2 += salpha[n] * *(const f32x4*)(ep + (size_t)n * ENC_DIM);
    *(f32x4*)(out + (size_t)b * ENC_DIM + tid * 4) = a2;
}

// ---------------------------------------------------------------------------
extern "C" void kernel_launch(void* const* d_in, const int* in_sizes, int n_in,
                              void* d_out, int out_size, void* d_ws, size_t ws_size,
                              hipStream_t stream) {
    const float* enc    = (const float*)d_in[0];
    const float* hidden = (const float*)d_in[1];
    const float* Wenc   = (const float*)d_in[2];
    const float* benc   = (const float*)d_in[3];
    const float* Wdec   = (const float*)d_in[4];
    const float* bdec   = (const float*)d_in[5];
    const float* Wfull  = (const float*)d_in[6];
    // d_in[7] = b_full: softmax-shift-invariant, unused.
    float* out = (float*)d_out;

    unsigned short* Wp    = (unsigned short*)d_ws;                   // 2 MB
    float*          att2p = (float*)((char*)d_ws + (2u << 20));      // 512 KB

    pack_wenc   <<<512, 256, 0, stream>>>(Wenc, Wp);
    att2_kernel <<<BATCH, 256, 0, stream>>>(hidden, Wdec, bdec, benc, att2p);
    fused_kernel<<<BATCH, 512, 0, stream>>>(enc, Wp, att2p, Wfull, out);
}